// Round 6
// baseline (772.087 us; speedup 1.0000x reference)
//
#include <hip/hip_runtime.h>

#define TEMP 0.05f
#define EPS 1e-8f
#define NROWS 16384
#define DDIM 1024

typedef float f32x4 __attribute__((ext_vector_type(4)));

// Single fused kernel. One row per 256-thread block (structure identical to
// R5 rows kernel, which sits at the measured ~3.3 TB/s delivered-read
// ceiling). The cross-block reduction is fused via device-scope atomics with
// poison-aware baselines (d_ws is re-poisoned to 0xAA before every launch):
//   ws[0] (float): accumulator, starts at bits 0xAAAAAAAA = -3.03e-13
//   ws[1] (u32)  : block counter, starts at 0xAAAAAAAA
__global__ __launch_bounds__(256) void byol_fused_kernel(
        const float* __restrict__ a, const float* __restrict__ b,
        float* __restrict__ out, float* __restrict__ ws) {
    const int row  = blockIdx.x;
    const int t    = threadIdx.x;
    const int wave = t >> 6;
    const int lane = t & 63;

    const f32x4* a4 = (const f32x4*)(a) + (size_t)row * (DDIM / 4) + t;
    const f32x4* b4 = (const f32x4*)(b) + (size_t)row * (DDIM / 4) + t;

    f32x4 av = *a4;
    f32x4 bv = *b4;

    float dot = av.x * bv.x + av.y * bv.y + av.z * bv.z + av.w * bv.w;
    float aa  = av.x * av.x + av.y * av.y + av.z * av.z + av.w * av.w;
    float bb  = bv.x * bv.x + bv.y * bv.y + bv.z * bv.z + bv.w * bv.w;

    // Wave-level butterfly (6 steps x 3 values).
#pragma unroll
    for (int off = 32; off > 0; off >>= 1) {
        dot += __shfl_xor(dot, off, 64);
        aa  += __shfl_xor(aa,  off, 64);
        bb  += __shfl_xor(bb,  off, 64);
    }

    // Cross-wave combine via LDS (4 waves).
    __shared__ float s[12];
    if (lane == 0) {
        s[wave]     = dot;
        s[wave + 4] = aa;
        s[wave + 8] = bb;
    }
    __syncthreads();
    if (t == 0) {
        float d = s[0] + s[1] + s[2]  + s[3];
        float x = s[4] + s[5] + s[6]  + s[7];
        float y = s[8] + s[9] + s[10] + s[11];
        float n1 = fmaxf(sqrtf(x), EPS);
        float n2 = fmaxf(sqrtf(y), EPS);
        float loss = 2.0f - 2.0f * (d / (n1 * n2));

        float*        acc = ws;
        unsigned int* cnt = (unsigned int*)(ws + 1);

        atomicAdd(acc, loss);       // device-scope by default
        __threadfence();            // acc add visible before counter bump
        unsigned int old = atomicAdd(cnt, 1u);
        // Counter starts at poison 0xAAAAAAAA; the last (NROWS-th) arrival
        // reads back 0xAAAAAAAA + NROWS - 1 (unsigned wrap is well-defined).
        if (old == 0xAAAAAAAAu + (unsigned int)(NROWS - 1)) {
            __threadfence();
            float total = atomicAdd(acc, 0.0f);   // atomic read of final sum
            // Remove the poison baseline (-3.03e-13) for exactness; harmless.
            total -= __uint_as_float(0xAAAAAAAAu);
            out[0] = total * (1.0f / ((float)NROWS * TEMP));
        }
    }
}

extern "C" void kernel_launch(void* const* d_in, const int* in_sizes, int n_in,
                              void* d_out, int out_size, void* d_ws, size_t ws_size,
                              hipStream_t stream) {
    const float* a = (const float*)d_in[0];
    const float* b = (const float*)d_in[1];
    float* out = (float*)d_out;
    float* ws  = (float*)d_ws;

    byol_fused_kernel<<<NROWS, 256, 0, stream>>>(a, b, out, ws);
}